// Round 5
// baseline (416.820 us; speedup 1.0000x reference)
//
#include <hip/hip_runtime.h>

#define NN    8192
#define NL    16
#define NE    (NN * 128)
#define NOUTC 16
#define EOUTC (NN * NOUTC)

#define SBLK  256            // scatter blocks
#define STHR  1024           // scatter threads (16 waves)
#define EPB   (NE / SBLK)    // 4096 edges per block per layer

#define RBLK  512            // reduce blocks (16 neurons each)
#define RTHR  256

__device__ __forceinline__ float lrelu(float v) { return v >= 0.f ? v : 0.01f * v; }

// ---- scatter: gather(LDS) -> LDS private acc -> coalesced dense partial write ----
__global__ __launch_bounds__(STHR) void scatter_kernel(
    const float* __restrict__ sv,       // activated source vector (x or accv)
    const int*   __restrict__ es,
    const int*   __restrict__ ed,
    const float* __restrict__ ew,
    float*       __restrict__ partials) // [SBLK][NN]
{
    __shared__ float vals[NN];
    __shared__ float accs[NN];
    const int tid = threadIdx.x;
    const int b   = blockIdx.x;

    // stage 8192 floats: 2 coalesced float4 loads per thread; zero private acc
    {
        const int i0 = tid * 4;             // 0..4095
        const int i1 = 4096 + tid * 4;      // 4096..8191
        *(float4*)(vals + i0) = *(const float4*)(sv + i0);
        *(float4*)(vals + i1) = *(const float4*)(sv + i1);
        *(float4*)(accs + i0) = make_float4(0.f, 0.f, 0.f, 0.f);
        *(float4*)(accs + i1) = make_float4(0.f, 0.f, 0.f, 0.f);
    }
    __syncthreads();

    // one edge quad per thread (STHR*4 == EPB)
    {
        const int e = b * EPB + tid * 4;
        int4   s = *(const int4*)(es + e);
        int4   d = *(const int4*)(ed + e);
        float4 w = *(const float4*)(ew + e);
        atomicAdd(&accs[d.x], vals[s.x] * w.x);
        atomicAdd(&accs[d.y], vals[s.y] * w.y);
        atomicAdd(&accs[d.z], vals[s.z] * w.z);
        atomicAdd(&accs[d.w], vals[s.w] * w.w);
    }
    __syncthreads();

    // coalesced dense flush of the private partial
    {
        float* prow = partials + (size_t)b * NN;
        const int i0 = tid * 4;
        const int i1 = 4096 + tid * 4;
        *(float4*)(prow + i0) = *(const float4*)(accs + i0);
        *(float4*)(prow + i1) = *(const float4*)(accs + i1);
    }
}

// ---- reduce 256 partial rows -> activated layer vector (block owns 16 neurons) ----
__global__ __launch_bounds__(RTHR) void reduce_kernel(
    const float* __restrict__ partials,  // [SBLK][NN]
    float*       __restrict__ accv)      // [NN], activated
{
    __shared__ float sred[64][17];
    __shared__ float sred2[4][17];
    const int b  = blockIdx.x;           // 512 blocks, 16 neurons each
    const int c  = threadIdx.x & 3;      // float4 column within block span
    const int kg = threadIdx.x >> 2;     // 0..63 row group

    const float* p0 = partials + (size_t)kg * NN + (size_t)(b * 4 + c) * 4;
    float4 s = make_float4(0.f, 0.f, 0.f, 0.f);
    #pragma unroll
    for (int j = 0; j < 4; ++j) {        // rows kg + 64*j
        float4 v = *(const float4*)(p0 + (size_t)j * 64 * NN);
        s.x += v.x; s.y += v.y; s.z += v.z; s.w += v.w;
    }
    sred[kg][c * 4 + 0] = s.x;
    sred[kg][c * 4 + 1] = s.y;
    sred[kg][c * 4 + 2] = s.z;
    sred[kg][c * 4 + 3] = s.w;
    __syncthreads();

    if (threadIdx.x < 64) {
        const int col = threadIdx.x & 15, g = threadIdx.x >> 4;  // 4 groups of 16 rows
        float t = 0.f;
        #pragma unroll
        for (int r = 0; r < 16; ++r) t += sred[g * 16 + r][col];
        sred2[g][col] = t;
    }
    __syncthreads();

    if (threadIdx.x < 16) {
        float t = sred2[0][threadIdx.x] + sred2[1][threadIdx.x]
                + sred2[2][threadIdx.x] + sred2[3][threadIdx.x];
        accv[b * 16 + threadIdx.x] = lrelu(t);
    }
}

// ---- output scatter: one edge per thread, 16 LDS bins -> outs[b][16] ----
__global__ __launch_bounds__(512) void out_scatter_kernel(
    const float* __restrict__ accv,      // activated layer-15 vector
    const int*   __restrict__ out_src,
    const int*   __restrict__ out_dst,
    const float* __restrict__ out_w,
    float*       __restrict__ outs)      // [256][NOUTC]
{
    __shared__ float bins[NOUTC];
    const int tid = threadIdx.x;
    if (tid < NOUTC) bins[tid] = 0.f;
    __syncthreads();
    const int g = blockIdx.x * 512 + tid;           // EOUTC == 256*512 exactly
    atomicAdd(&bins[out_dst[g]], accv[out_src[g]] * out_w[g]);
    __syncthreads();
    if (tid < NOUTC) outs[(size_t)blockIdx.x * NOUTC + tid] = bins[tid];
}

// ---- final: reduce 256x16, lrelu, softmax ----
__global__ __launch_bounds__(256) void final_kernel(
    const float* __restrict__ outs, float* __restrict__ out)
{
    __shared__ float red[16][17];
    const int tid = threadIdx.x;
    const int j = tid & 15, g = tid >> 4;            // 16 groups x 16 bins
    float s = 0.f;
    #pragma unroll
    for (int r = 0; r < 256 / 16; ++r)
        s += outs[(size_t)(g + r * 16) * NOUTC + j];
    red[g][j] = s;
    __syncthreads();
    if (tid < NOUTC) {
        float t = 0.f;
        #pragma unroll
        for (int g2 = 0; g2 < 16; ++g2) t += red[g2][tid];
        float v = lrelu(t);
        float m = v;
        #pragma unroll
        for (int off = 8; off >= 1; off >>= 1)
            m = fmaxf(m, __shfl_xor(m, off, 64));
        float e = __expf(v - m);
        float ssum = e;
        #pragma unroll
        for (int off = 8; off >= 1; off >>= 1)
            ssum += __shfl_xor(ssum, off, 64);
        out[tid] = e / ssum;
    }
}

extern "C" void kernel_launch(void* const* d_in, const int* in_sizes, int n_in,
                              void* d_out, int out_size, void* d_ws, size_t ws_size,
                              hipStream_t stream) {
    const float* x        = (const float*)d_in[0];
    const float* edge_w   = (const float*)d_in[1];
    const float* out_w    = (const float*)d_in[2];
    const int*   edge_src = (const int*)d_in[3];
    const int*   edge_dst = (const int*)d_in[4];
    const int*   out_src  = (const int*)d_in[5];
    const int*   out_dst  = (const int*)d_in[6];

    float* partials = (float*)d_ws;                     // SBLK*NN floats (8 MB)
    float* accv     = partials + (size_t)SBLK * NN;     // NN floats
    float* outs     = accv + NN;                        // 256*NOUTC floats
    float* out      = (float*)d_out;

    for (int l = 0; l < NL; ++l) {
        const float* sv = (l == 0) ? x : accv;
        scatter_kernel<<<SBLK, STHR, 0, stream>>>(
            sv,
            edge_src + (size_t)l * NE,
            edge_dst + (size_t)l * NE,
            edge_w   + (size_t)l * NE,
            partials);
        reduce_kernel<<<RBLK, RTHR, 0, stream>>>(partials, accv);
    }

    out_scatter_kernel<<<256, 512, 0, stream>>>(accv, out_src, out_dst, out_w, outs);
    final_kernel<<<1, 256, 0, stream>>>(outs, out);
}